// Round 20
// baseline (115.550 us; speedup 1.0000x reference)
//
#include <hip/hip_runtime.h>

// SigLIP contrastive loss:
//   logits = emb1 @ emb2^T / 0.07           [B,B], B=8192, D=1024
//   loss = ( sum_i softplus(-l_ii) + sum_{i!=j} softplus(l_ij) ) / B
// R20: 4 waves/SIMD. R18/R19 pinned at 3 waves/SIMD by registers (148/wave:
// acc 64 + frags 64 + addr). Halve the accumulator: wave = 32x64 (acc 32),
// 8-wave 512-thread blocks, same 128x128 tile + 48 KB LDS (A dbuf 32K, B
// single 16K) -> 2 blocks/CU = 4 waves/SIMD, cap 128 >= demand ~100.
// Cost: 96 b128 LDS reads/block-K-tile (1152 cyc/CU) vs 768 — still under
// the expected ~1300-cyc period. Sync protocol identical to R18.

#define B_DIM 8192
#define K_DIM 1024
#define BT 128                 // tile rows == cols
#define BKB 128                // K bytes per K-tile
#define NT (K_DIM / BKB)       // 8 K-tiles
#define BRICK 16384            // one (128-row panel, K-tile) brick
#define PANEL_BYTES (NT * BRICK)

typedef int i32x4 __attribute__((ext_vector_type(4)));
typedef int i32x8 __attribute__((ext_vector_type(8)));
typedef float f32x4 __attribute__((ext_vector_type(4)));

// f32 -> fp8 e4m3 brick permutation (PANEL=128). One thread = 16 out bytes.
// Brick offset = fb*2048 + h*1024 + kch*256 + lr*16.
// Source: row = p*128 + fb*16 + lr, k byte = t*128 + kch*32 + h*16.
__device__ __forceinline__ void brick_store(const float* __restrict__ in,
                                            unsigned char* __restrict__ out,
                                            float scale, int i) {
  const int o = i * 16;
  const int b = o >> 14;                  // brick index
  const int p = b >> 3, t = b & 7;        // panel, K-tile
  const int w = o & (BRICK - 1);
  const int fb = w >> 11;
  const int h = (w >> 10) & 1;
  const int kch = (w >> 8) & 3;
  const int lr = (w >> 4) & 15;
  const int row = p * 128 + fb * 16 + lr;
  const int kb = t * 128 + kch * 32 + h * 16;
  const float4* src = (const float4*)(in + (size_t)row * K_DIM + kb);
  float4 v0 = src[0], v1 = src[1], v2 = src[2], v3 = src[3];
  unsigned w0 = 0, w1 = 0, w2 = 0, w3 = 0;
  w0 = __builtin_amdgcn_cvt_pk_fp8_f32(v0.x * scale, v0.y * scale, w0, 0);
  w0 = __builtin_amdgcn_cvt_pk_fp8_f32(v0.z * scale, v0.w * scale, w0, 1);
  w1 = __builtin_amdgcn_cvt_pk_fp8_f32(v1.x * scale, v1.y * scale, w1, 0);
  w1 = __builtin_amdgcn_cvt_pk_fp8_f32(v1.z * scale, v1.w * scale, w1, 1);
  w2 = __builtin_amdgcn_cvt_pk_fp8_f32(v2.x * scale, v2.y * scale, w2, 0);
  w2 = __builtin_amdgcn_cvt_pk_fp8_f32(v2.z * scale, v2.w * scale, w2, 1);
  w3 = __builtin_amdgcn_cvt_pk_fp8_f32(v3.x * scale, v3.y * scale, w3, 0);
  w3 = __builtin_amdgcn_cvt_pk_fp8_f32(v3.z * scale, v3.w * scale, w3, 1);
  *(uint4*)(out + o) = make_uint4(w0, w1, w2, w3);
}

__global__ __launch_bounds__(256) void cvt_fused(
    const float* __restrict__ e1, const float* __restrict__ e2,
    unsigned char* __restrict__ A8, unsigned char* __restrict__ B8,
    int nbA, float scaleA) {
  const int blk = blockIdx.x;
  if (blk < nbA)
    brick_store(e1, A8, scaleA, blk * 256 + threadIdx.x);
  else
    brick_store(e2, B8, 1.0f, (blk - nbA) * 256 + threadIdx.x);
}

// Cheap softplus accumulate: softplus(x) = max(x,0) + log(1+exp(-|x|)).
template <bool DIAG>
__device__ __forceinline__ float softplus_sum(const f32x4 (&acc)[2][4],
                                              int rbase, int cbase) {
  float lin = 0.f, cor = 0.f;
#pragma unroll
  for (int m = 0; m < 2; ++m) {
#pragma unroll
    for (int n = 0; n < 4; ++n) {
#pragma unroll
      for (int r = 0; r < 4; ++r) {
        float x = acc[m][n][r];
        if (DIAG) {
          int row = rbase + m * 16 + r;
          int col = cbase + n * 16;
          if (row == col) x = -x;  // diagonal: softplus(-l_ii)
        }
        lin += fmaxf(x, 0.f);
        cor += __logf(1.f + __expf(-fabsf(x)));
      }
    }
  }
  return lin + cor;
}

// Staging: per K-tile A 16 KB + B 16 KB as 1 KB slices; 8 waves take 2
// slices of each. LDS map: A dbuf [0,16K)+[16K,32K), B single [32K,48K).
#define STAGEA(SB, Q, TI)                                                     \
  __builtin_amdgcn_global_load_lds(                                           \
      (const __attribute__((address_space(1))) void*)(const void*)(           \
          srcA + (TI) * BRICK + (Q) * 1024),                                  \
      (__attribute__((address_space(3))) void*)(void*)(                       \
          lds + (SB) + dAW + (Q) * 1024),                                     \
      16, 0, 0)
#define STAGEB(Q, TI)                                                         \
  __builtin_amdgcn_global_load_lds(                                           \
      (const __attribute__((address_space(1))) void*)(const void*)(           \
          srcB + (TI) * BRICK + (Q) * 1024),                                  \
      (__attribute__((address_space(3))) void*)(void*)(                       \
          lds + 32768 + dAW + (Q) * 1024),                                    \
      16, 0, 0)
#define STG2A(SB, TI) STAGEA(SB, 0, TI); STAGEA(SB, 1, TI)
#define STG2B(TI) STAGEB(0, TI); STAGEB(1, TI)

// Fragment read: two conflict-free ds_read_b128 (lane*16 stride) + combine.
#define LDA(OUT, AB, M)                                                       \
  {                                                                           \
    const unsigned char* _b = ldsL + ((AB) + ((wr * 2 + (M)) << 11));         \
    i32x4 _lo = *(const i32x4*)(_b);                                          \
    i32x4 _hi = *(const i32x4*)(_b + 1024);                                   \
    OUT = __builtin_shufflevector(_lo, _hi, 0, 1, 2, 3, 4, 5, 6, 7);          \
  }
#define LDB(OUT, N)                                                           \
  {                                                                           \
    const unsigned char* _b = ldsL + (32768 + ((wc * 4 + (N)) << 11));        \
    i32x4 _lo = *(const i32x4*)(_b);                                          \
    i32x4 _hi = *(const i32x4*)(_b + 1024);                                   \
    OUT = __builtin_shufflevector(_lo, _hi, 0, 1, 2, 3, 4, 5, 6, 7);          \
  }

#define MFMA(AF, BF, M, N)                                                    \
  acc[M][N] = __builtin_amdgcn_mfma_scale_f32_16x16x128_f8f6f4(               \
      AF, BF, acc[M][N], 0, 0, 0, 127, 0, 127)

__global__ __launch_bounds__(512, 4) void siglip_gemm(
    const unsigned char* __restrict__ A8,
    const unsigned char* __restrict__ B8,
    float* __restrict__ partials) {
  __shared__ unsigned char lds[49152];  // A dbuf 32K | B single 16K

  const int tid = threadIdx.x;
  const int wave = tid >> 6;
  const int lane = tid & 63;
  const int wr = wave >> 1;  // 0..3 -> 32-row strip
  const int wc = wave & 1;   // 0..1 -> 64-col strip
  const int brow = blockIdx.y;
  const int bcol = blockIdx.x;

  f32x4 acc[2][4];
#pragma unroll
  for (int m = 0; m < 2; ++m)
#pragma unroll
    for (int n = 0; n < 4; ++n) acc[m][n] = f32x4{0.f, 0.f, 0.f, 0.f};

  const unsigned char* srcA =
      A8 + (size_t)brow * PANEL_BYTES + wave * 2048 + (lane << 4);
  const unsigned char* srcB =
      B8 + (size_t)bcol * PANEL_BYTES + wave * 2048 + (lane << 4);
  const int dAW = wave * 2048;                   // wave's staging sub-region
  const unsigned char* ldsL = lds + (lane << 4); // per-lane read base

  // Prologue: stage tile 0 (A -> abuf0, B -> bbuf), drain, publish.
  STG2A(0, 0); STG2B(0);
  asm volatile("s_waitcnt vmcnt(0)" ::: "memory");
  __builtin_amdgcn_s_barrier();
  __builtin_amdgcn_sched_barrier(0);

#pragma unroll
  for (int T = 0; T < NT; ++T) {
    const int ab = (T & 1) * 16384;   // A read buffer (tile T)
    const int sab = ab ^ 16384;       // A stage buffer (holds consumed T-1)

    // B fragment reads for tile T (single-buffered: must drain before the
    // B overwrite below). A staging issues now -> latency hides under the
    // barrier + MFMA cluster.
    i32x8 b0, b1, b2, b3;
    LDB(b0, 0); LDB(b1, 1); LDB(b2, 2); LDB(b3, 3);
    if (T < NT - 1) { STG2A(sab, T + 1); }

    // Own B reads in regs, then join: all waves' B(T) reads are complete.
    asm volatile("s_waitcnt lgkmcnt(0)" ::: "memory");
    __builtin_amdgcn_s_barrier();
    __builtin_amdgcn_sched_barrier(0);

    // B(T+1) overwrite now safe. A reads (dbuf, no hazard) issue here and
    // interleave into the MFMA cluster via compiler counted lgkmcnt.
    if (T < NT - 1) { STG2B(T + 1); }
    i32x8 a0, a1;
    LDA(a0, ab, 0); LDA(a1, ab, 1);

    __builtin_amdgcn_s_setprio(1);
    MFMA(a0, b0, 0, 0); MFMA(a0, b1, 0, 1); MFMA(a0, b2, 0, 2); MFMA(a0, b3, 0, 3);
    MFMA(a1, b0, 1, 0); MFMA(a1, b1, 1, 1); MFMA(a1, b2, 1, 2); MFMA(a1, b3, 1, 3);
    __builtin_amdgcn_s_setprio(0);

    if (T < NT - 1) {
      // Own staging of T+1 (A and B) landed; barrier publishes cross-wave.
      asm volatile("s_waitcnt vmcnt(0)" ::: "memory");
      __builtin_amdgcn_s_barrier();
      __builtin_amdgcn_sched_barrier(0);
    }
  }

  // Epilogue. C/D 16x16 map: col = lane&15, row = (lane>>4)*4 + r.
  const int rbase = brow * BT + wr * 32 + (lane >> 4) * 4;
  const int cbase = bcol * BT + wc * 64 + (lane & 15);
  float lsum;
  if (brow == bcol)
    lsum = softplus_sum<true>(acc, rbase, cbase);
  else
    lsum = softplus_sum<false>(acc, rbase, cbase);

#pragma unroll
  for (int off = 32; off > 0; off >>= 1) lsum += __shfl_down(lsum, off);

  // Reuse the (dead) B buffer for cross-wave reduction (keeps LDS at 48 KB).
  float* wsum = (float*)(lds + 32768);
  __syncthreads();
  if (lane == 0) wsum[wave] = lsum;
  __syncthreads();
  if (tid == 0) {
    float s = 0.f;
#pragma unroll
    for (int w = 0; w < 8; ++w) s += wsum[w];
    partials[blockIdx.y * gridDim.x + blockIdx.x] = s;
  }
}

__global__ void reduce_kernel(const float* __restrict__ partials, int n,
                              float* __restrict__ out) {
  __shared__ float s[256];
  float v = 0.f;
  for (int i = threadIdx.x; i < n; i += 256) v += partials[i];
  s[threadIdx.x] = v;
  __syncthreads();
  for (int off = 128; off > 0; off >>= 1) {
    if ((int)threadIdx.x < off) s[threadIdx.x] += s[threadIdx.x + off];
    __syncthreads();
  }
  if (threadIdx.x == 0) out[0] = s[0] / (float)B_DIM;
}

extern "C" void kernel_launch(void* const* d_in, const int* in_sizes, int n_in,
                              void* d_out, int out_size, void* d_ws, size_t ws_size,
                              hipStream_t stream) {
  const float* emb1 = (const float*)d_in[0];
  const float* emb2 = (const float*)d_in[1];

  unsigned char* A8 = (unsigned char*)d_ws;                // 8 MB (bricked)
  unsigned char* B8 = A8 + (size_t)B_DIM * K_DIM;          // 8 MB (bricked)
  float* partials = (float*)(B8 + (size_t)B_DIM * K_DIM);  // 16 KB

  const float INV_T = 1.0f / 0.07f;
  const int nbA = (B_DIM * K_DIM / 16) / 256;  // 2048 blocks per operand
  cvt_fused<<<2 * nbA, 256, 0, stream>>>(emb1, emb2, A8, B8, nbA, INV_T);

  dim3 grid(B_DIM / BT, B_DIM / BT);  // 64 x 64
  siglip_gemm<<<grid, 512, 0, stream>>>(A8, B8, partials);

  const int nparts = (B_DIM / BT) * (B_DIM / BT);
  reduce_kernel<<<1, 256, 0, stream>>>(partials, nparts, (float*)d_out);
}